// Round 25
// baseline (196.400 us; speedup 1.0000x reference)
//
#include <hip/hip_runtime.h>

using short8 = __attribute__((ext_vector_type(8))) short;
using f32x4  = __attribute__((ext_vector_type(4))) float;

#define DEV __device__ __forceinline__

#define GLBP(p) ((const __attribute__((address_space(1))) unsigned int*)(p))
#define LDSP(p) ((__attribute__((address_space(3))) unsigned int*)(p))

#define EXP2F(x) __builtin_amdgcn_exp2f(x)

// float -> bf16 round-to-nearest-even (finite inputs)
DEV unsigned short f2bf(float f) {
    unsigned int u = __float_as_uint(f);
    u += 0x7fffu + ((u >> 16) & 1u);
    return (unsigned short)(u >> 16);
}

// pack two floats into 2 bf16 (RNE), lo | hi<<16
DEV unsigned int pack2bf(float a, float b) {
    unsigned int ua = __float_as_uint(a);
    ua += 0x7fffu + ((ua >> 16) & 1u);
    unsigned int ub = __float_as_uint(b);
    ub += 0x7fffu + ((ub >> 16) & 1u);
    return (ua >> 16) | (ub & 0xffff0000u);
}

// ---------------------------------------------------------------- converts
// merged transpose+convert for BOTH weights: z=0 -> W_lin[layer] (1024x768),
// z=1 -> W_q (768x768).  out bf16 [C][R].
__global__ __launch_bounds__(256) void wt2_k(const float* __restrict__ Wl,
                                             const float* __restrict__ Wq,
                                             unsigned short* __restrict__ outl,
                                             unsigned short* __restrict__ outq,
                                             const int* __restrict__ layerp) {
    const int z = blockIdx.z;
    int R, C;
    const float* in;
    unsigned short* out;
    if (z == 0) {
        R = 1024; C = 768;
        in = Wl + (size_t)layerp[0] * (1024 * 768);
        out = outl;
    } else {
        if (blockIdx.y >= 24) return;   // 768/32 = 24 row-tiles
        R = 768; C = 768;
        in = Wq;
        out = outq;
    }
    __shared__ float t[32][33];
    const int tx = threadIdx.x & 31, ty = threadIdx.x >> 5;
    const int c0 = blockIdx.x * 32, r0 = blockIdx.y * 32;
#pragma unroll
    for (int it = 0; it < 4; ++it)
        t[ty + it * 8][tx] = in[(size_t)(r0 + ty + it * 8) * C + c0 + tx];
    __syncthreads();
#pragma unroll
    for (int it = 0; it < 4; ++it)
        out[(size_t)(c0 + ty + it * 8) * R + r0 + tx] = f2bf(t[tx][ty + it * 8]);
}

// bf16 [b][2048][H*96] -> bf16 [b*H + h][96][2048]
__global__ __launch_bounds__(256) void kvt_k(const unsigned short* __restrict__ kv,
                                             unsigned short* __restrict__ kvT) {
    const int n0 = blockIdx.x * 32, d0 = blockIdx.y * 32, bh = blockIdx.z;
    const int b = bh >> 3, h = bh & 7;
    __shared__ unsigned short t[32][33];
    const int tx = threadIdx.x & 31, ty = threadIdx.x >> 5;
#pragma unroll
    for (int it = 0; it < 4; ++it)
        t[ty + it * 8][tx] = kv[(size_t)(b * 2048 + n0 + ty + it * 8) * 768 + h * 96 + d0 + tx];
    __syncthreads();
#pragma unroll
    for (int it = 0; it < 4; ++it)
        kvT[((size_t)bh * 96 + d0 + ty + it * 8) * 2048 + n0 + tx] = t[tx][ty + it * 8];
}

// ---------------------------------------------------------------- GEMM (dual)
// R25: tile 64x96, grid (128, 8, 2) = 2048 blocks = 8 blocks/CU (was 2-4).
// Theory: the 2-barrier/iter structure is convergence+latency bound; R24 proved
// bigger tiles don't help (76us @ 2/CU); more independent barrier domains per CU
// should.  4 waves 2x2, wave tile 32x48, acc[2][3], BK=32.
// A: fp32 reg-staged + fused f2bf; thread tid -> cell (kg=tid>>6, srow=tid&63);
//    each wave = one kg-plane, lane-linear ds_write (conflict-free); plane
//    stride 66 cells staggers frag-read banks.
// B: global_load_lds, 384 cells linear (c=tid, +256 for tid<128).
__global__ __launch_bounds__(256) void gemm_dual(const float* __restrict__ A0,
                                                 const unsigned short* __restrict__ B0,
                                                 float* __restrict__ C0,
                                                 const float* __restrict__ A1,
                                                 const unsigned short* __restrict__ B1,
                                                 unsigned short* __restrict__ C1,
                                                 const float* __restrict__ bias,
                                                 float oscale) {
    __shared__ unsigned short smA[2112];   // 4 kg-planes x 66 cells x 8 shorts
    __shared__ unsigned short smB[3072];   // 4 kg-planes x 96 cells x 8 shorts (linear)
    const int z = blockIdx.z;
    const float* A = z ? A1 : A0;
    const unsigned short* B = z ? B1 : B0;
    const int K = z ? 768 : 1024;
    const int tid = threadIdx.x, lane = tid & 63;
    const int l15 = lane & 15, g = lane >> 4;
    const int w = tid >> 6, wm = w >> 1, wn = w & 1;
    const int m0 = blockIdx.x * 64, n0 = blockIdx.y * 96;
    const int skg = tid >> 6, srow = tid & 63;   // A: 1 cell/thread
    const int c1 = tid + 256;
    const unsigned short* pB0 = B + (size_t)(n0 + tid % 96) * K + (tid / 96) * 8;
    const unsigned short* pB1 = B + (size_t)(n0 + c1 % 96) * K + (c1 / 96) * 8;
    const float* pA = A + (size_t)(m0 + srow) * K + skg * 8;
    f32x4 acc[2][3] = {};
    const int nkt = K >> 5;
    for (int kt = 0; kt < nkt; ++kt) {
        const int k0 = kt << 5;
        __syncthreads();
        {
            __builtin_amdgcn_global_load_lds(GLBP(pB0 + k0), LDSP(smB + tid * 8), 16, 0, 0);
            if (tid < 128)
                __builtin_amdgcn_global_load_lds(GLBP(pB1 + k0), LDSP(smB + c1 * 8), 16, 0, 0);
            float4 a0 = *(const float4*)(pA + k0);
            float4 a1 = *(const float4*)(pA + k0 + 4);
            short8 va;
            va[0] = f2bf(a0.x); va[1] = f2bf(a0.y); va[2] = f2bf(a0.z); va[3] = f2bf(a0.w);
            va[4] = f2bf(a1.x); va[5] = f2bf(a1.y); va[6] = f2bf(a1.z); va[7] = f2bf(a1.w);
            *(short8*)(smA + (skg * 66 + srow) * 8) = va;
        }
        __syncthreads();
        short8 af[2], bf[3];
#pragma unroll
        for (int i = 0; i < 2; ++i)
            af[i] = *(const short8*)(smA + (g * 66 + wm * 32 + i * 16 + l15) * 8);
#pragma unroll
        for (int j = 0; j < 3; ++j)
            bf[j] = *(const short8*)(smB + (g * 96 + wn * 48 + j * 16 + l15) * 8);
        __builtin_amdgcn_s_setprio(1);
#pragma unroll
        for (int i = 0; i < 2; ++i)
#pragma unroll
            for (int j = 0; j < 3; ++j)
                acc[i][j] = __builtin_amdgcn_mfma_f32_16x16x32_bf16(af[i], bf[j], acc[i][j], 0, 0, 0);
        __builtin_amdgcn_s_setprio(0);
    }
#pragma unroll
    for (int j = 0; j < 3; ++j) {
        const int col = n0 + wn * 48 + j * 16 + l15;
        const float bv = z ? bias[col] : 0.0f;
#pragma unroll
        for (int i = 0; i < 2; ++i)
#pragma unroll
            for (int r = 0; r < 4; ++r) {
                const int row = m0 + wm * 32 + i * 16 + g * 4 + r;
                if (z == 0) {
                    C0[(size_t)row * 768 + col] = acc[i][j][r];
                } else {
                    const float v = (acc[i][j][r] + bv) * oscale;
                    C1[(size_t)row * 768 + col] = f2bf(v);
                }
            }
    }
}

// ---------------------------------------------------------------- row norms
// one wave per 768-elem row
__global__ __launch_bounds__(256) void rownorm_k(const float* __restrict__ in,
                                                 float* __restrict__ outf,
                                                 unsigned short* __restrict__ outb) {
    const int lane = threadIdx.x & 63;
    const int row = blockIdx.x * 4 + (threadIdx.x >> 6);
    const float* p = in + (size_t)row * 768;
    float4 v[3];
    float s = 0.f;
#pragma unroll
    for (int i = 0; i < 3; ++i) {
        v[i] = ((const float4*)p)[i * 64 + lane];
        s += v[i].x * v[i].x + v[i].y * v[i].y + v[i].z * v[i].z + v[i].w * v[i].w;
    }
#pragma unroll
    for (int mask = 1; mask < 64; mask <<= 1) s += __shfl_xor(s, mask);
    const float inv = rsqrtf(s);
    float4* of = (float4*)(outf + (size_t)row * 768);
    ushort4* ob = (ushort4*)(outb + (size_t)row * 768);
#pragma unroll
    for (int i = 0; i < 3; ++i) {
        float4 q;
        q.x = v[i].x * inv; q.y = v[i].y * inv; q.z = v[i].z * inv; q.w = v[i].w * inv;
        of[i * 64 + lane] = q;
        ushort4 u;
        u.x = f2bf(q.x); u.y = f2bf(q.y); u.z = f2bf(q.z); u.w = f2bf(q.w);
        ob[i * 64 + lane] = u;
    }
}

// residual + L2 norm; attn-out is bf16 (halved traffic), residual Ft is fp32
__global__ __launch_bounds__(256) void resid_norm_k(const unsigned short* __restrict__ in,
                                                    const float* __restrict__ res,
                                                    float* __restrict__ outf) {
    const int lane = threadIdx.x & 63;
    const int row = blockIdx.x * 4 + (threadIdx.x >> 6);
    const ushort4* pa = (const ushort4*)(in + (size_t)row * 768);
    const float4* pb = (const float4*)(res + (size_t)row * 768);
    float4 v[3];
    float s = 0.f;
#pragma unroll
    for (int i = 0; i < 3; ++i) {
        ushort4 a = pa[i * 64 + lane];
        float4 b = pb[i * 64 + lane];
        float4 c;
        c.x = __uint_as_float((unsigned int)a.x << 16) + b.x;
        c.y = __uint_as_float((unsigned int)a.y << 16) + b.y;
        c.z = __uint_as_float((unsigned int)a.z << 16) + b.z;
        c.w = __uint_as_float((unsigned int)a.w << 16) + b.w;
        v[i] = c;
        s += c.x * c.x + c.y * c.y + c.z * c.z + c.w * c.w;
    }
#pragma unroll
    for (int mask = 1; mask < 64; mask <<= 1) s += __shfl_xor(s, mask);
    const float inv = rsqrtf(s);
    float4* of = (float4*)(outf + (size_t)row * 768);
#pragma unroll
    for (int i = 0; i < 3; ++i) {
        float4 q;
        q.x = v[i].x * inv; q.y = v[i].y * inv; q.z = v[i].z * inv; q.w = v[i].w * inv;
        of[i * 64 + lane] = q;
    }
}

// ---------------------------------------------------------------- fused attention
// grid = 256 (XCD-swizzled) = 1 block/CU; 8 waves x 32 q-rows (256 q/block).
// KV chunk = 64; K and V^T double-buffered in LDS via global_load_lds (R14 verified).
// R15: softmax denominator in the matrix pipe (o6 = P x ones MFMA).
// R18: bf16 output.  R19: no max tracking (scores provably bounded ~0.42 log2-units).
__global__ __launch_bounds__(512) void attn_k(const unsigned short* __restrict__ Q,
                                              const unsigned short* __restrict__ KV,
                                              const unsigned short* __restrict__ KVT,
                                              unsigned short* __restrict__ O) {
    __shared__ unsigned short sK[2][6144];   // 12 KiB per buffer
    __shared__ unsigned short sV[2][6144];   // 12 KiB per buffer
    __shared__ unsigned short plds[8][32][72];
    // bijective XCD swizzle for nwg=256: XCD x gets bids [x*32, (x+1)*32)
    const int hw = blockIdx.x;
    const int bid = (hw & 7) * 32 + (hw >> 3);
    const int qb = bid & 7, h = (bid >> 3) & 7, b = bid >> 6;
    const int tid = threadIdx.x, lane = tid & 63, w = tid >> 6;   // w = 0..7
    const int l15 = lane & 15, g = lane >> 4;
    const int q0 = qb * 256 + w * 32;
    unsigned short(*pw)[72] = plds[w];

    const unsigned short* kb = KV + (size_t)(b * 2048) * 768 + h * 96;
    const unsigned short* vb = KVT + (size_t)((b * 8 + h) * 96) * 2048;

    // all-ones bf16 B-operand for the l = P x 1 MFMA
    const short8 kOnes = {(short)0x3F80, (short)0x3F80, (short)0x3F80, (short)0x3F80,
                          (short)0x3F80, (short)0x3F80, (short)0x3F80, (short)0x3F80};

    // Q fragments (B-operand): q = q0 + mi*16 + l15, d = ks*32 + g*8
    short8 aq[2][3];
#pragma unroll
    for (int mi = 0; mi < 2; ++mi) {
        const unsigned short* qp = Q + (size_t)(b * 2048 + q0 + mi * 16 + l15) * 768 + h * 96 + g * 8;
#pragma unroll
        for (int ks = 0; ks < 3; ++ks) aq[mi][ks] = *(const short8*)(qp + ks * 32);
    }
    f32x4 o[2][6] = {};
    f32x4 o6[2] = {};                 // row-sum accumulator (softmax denominator)

    // ---- staging descriptors: 24 x 1KB loads, 3 per wave (li = p*8 + w).
    // li 0..11: K, ksub = li, r = lane.  li 12..23: V, j = li-12, i = j*64+lane.
    const unsigned short* sgp[3];
    int sstep[3], soff[3], sisk[3];
#pragma unroll
    for (int p = 0; p < 3; ++p) {
        const int li = p * 8 + w;   // wave-uniform
        if (li < 12) {
            sgp[p] = kb + (size_t)lane * 768 + li * 8;
            sstep[p] = 64 * 768;
            soff[p] = li * 512;     // shorts
            sisk[p] = 1;
        } else {
            const int j = li - 12;
            const int i = j * 64 + lane;
            const int kvsub = i / 96, d = i - kvsub * 96;
            sgp[p] = vb + (size_t)d * 2048 + kvsub * 8;
            sstep[p] = 64;
            soff[p] = j * 512;
            sisk[p] = 0;
        }
    }
    auto stage = [&](unsigned short* sKb, unsigned short* sVb) {
#pragma unroll
        for (int p = 0; p < 3; ++p) {
            __builtin_amdgcn_global_load_lds(GLBP(sgp[p]), LDSP((sisk[p] ? sKb : sVb) + soff[p]), 16, 0, 0);
            sgp[p] += sstep[p];
        }
    };

    stage(sK[0], sV[0]);
    __syncthreads();   // drains vmcnt, buffer 0 ready

    for (int c = 0; c < 32; ++c) {
        const int cur = c & 1;
        const unsigned short* sKb = sK[cur];
        const unsigned short* sVb = sV[cur];
        if (c < 31) stage(sK[cur ^ 1], sV[cur ^ 1]);

        // ---- QK^T (swapped): S^T[kv][q], q = mi*16 + l15 lane-local ----
        f32x4 s[2][4];
        __builtin_amdgcn_s_setprio(1);
#pragma unroll
        for (int t = 0; t < 4; ++t) {
            short8 k0 = *(const short8*)(sKb + ((0 + g) * 64 + t * 16 + l15) * 8);
            short8 k1 = *(const short8*)(sKb + ((4 + g) * 64 + t * 16 + l15) * 8);
            short8 k2 = *(const short8*)(sKb + ((8 + g) * 64 + t * 16 + l15) * 8);
#pragma unroll
            for (int mi = 0; mi < 2; ++mi) {
                f32x4 a = {};
                a = __builtin_amdgcn_mfma_f32_16x16x32_bf16(k0, aq[mi][0], a, 0, 0, 0);
                a = __builtin_amdgcn_mfma_f32_16x16x32_bf16(k1, aq[mi][1], a, 0, 0, 0);
                a = __builtin_amdgcn_mfma_f32_16x16x32_bf16(k2, aq[mi][2], a, 0, 0, 0);
                s[mi][t] = a;
            }
        }
        __builtin_amdgcn_s_setprio(0);
        // ---- softmax numerator: P = exp2(s), un-shifted (scores bounded ~0.42) ----
#pragma unroll
        for (int mi = 0; mi < 2; ++mi) {
#pragma unroll
            for (int t = 0; t < 4; ++t)
#pragma unroll
                for (int r = 0; r < 4; ++r)
                    s[mi][t][r] = EXP2F(s[mi][t][r]);
            // write P^T -> P[q][kv] (one ds_write_b64 per (mi,t))
#pragma unroll
            for (int t = 0; t < 4; ++t) {
                uint2 pk;
                pk.x = pack2bf(s[mi][t][0], s[mi][t][1]);
                pk.y = pack2bf(s[mi][t][2], s[mi][t][3]);
                *(uint2*)&pw[mi * 16 + l15][t * 16 + g * 4] = pk;
            }
        }
        // ---- PV: O[q][d] += P[q][kv] * V^T[d][kv];  l += P x ones ----
        __builtin_amdgcn_s_setprio(1);
#pragma unroll
        for (int half = 0; half < 2; ++half) {
            short8 pa[2];
#pragma unroll
            for (int mi = 0; mi < 2; ++mi) {
                pa[mi] = *(const short8*)&pw[mi * 16 + l15][half * 32 + g * 8];
                o6[mi] = __builtin_amdgcn_mfma_f32_16x16x32_bf16(pa[mi], kOnes, o6[mi], 0, 0, 0);
            }
#pragma unroll
            for (int dt = 0; dt < 6; ++dt) {
                short8 bv = *(const short8*)(sVb + ((half * 4 + g) * 96 + dt * 16 + l15) * 8);
#pragma unroll
                for (int mi = 0; mi < 2; ++mi)
                    o[mi][dt] = __builtin_amdgcn_mfma_f32_16x16x32_bf16(pa[mi], bv, o[mi][dt], 0, 0, 0);
            }
        }
        __builtin_amdgcn_s_setprio(0);
        __syncthreads();   // drains staging vmcnt; next buffer ready, this buffer free
    }
    // epilogue: normalize rows; denominator per-lane in o6; bf16 output
#pragma unroll
    for (int mi = 0; mi < 2; ++mi)
#pragma unroll
        for (int r = 0; r < 4; ++r) {
            const float inv = 1.0f / o6[mi][r];
            unsigned short* op = O + (size_t)(b * 2048 + q0 + mi * 16 + g * 4 + r) * 768 + h * 96 + l15;
#pragma unroll
            for (int dt = 0; dt < 6; ++dt) op[dt * 16] = f2bf(o[mi][dt][r] * inv);
        }
}

// ---------------------------------------------------------------- launch
// SCALE * log2(e): softmax runs in exp2 domain
#define SCALE_F 0.05205877254075156f

extern "C" void kernel_launch(void* const* d_in, const int* in_sizes, int n_in,
                              void* d_out, int out_size, void* d_ws, size_t ws_size,
                              hipStream_t stream) {
    const float* Ft = (const float*)d_in[0];   // [4,2048,768]
    const float* Fs = (const float*)d_in[1];   // [4,2048,1024]
    const float* Wl = (const float*)d_in[2];   // [4,1024,768]
    const float* Wq = (const float*)d_in[3];   // [768,768]
    const float* bq = (const float*)d_in[4];   // [768]
    const int* layer = (const int*)d_in[5];    // scalar

    float* out0 = (float*)d_out;               // F_t_a [4,2048,768]
    float* out1 = out0 + 6291456;              // F_s_p [4,2048,768]

    char* ws = (char*)d_ws;
    unsigned short* wsQ   = (unsigned short*)(ws);              // 12,582,912 B
    unsigned short* wsWlt = (unsigned short*)(ws + 12582912);   //  1,572,864
    unsigned short* wsWqt = (unsigned short*)(ws + 14155776);   //  1,179,648
    unsigned short* wsKV  = (unsigned short*)(ws + 15335424);   // 12,582,912
    unsigned short* wsKVT = (unsigned short*)(ws + 27918336);   // 12,582,912
    float*          wsTmp = (float*)(ws + 40501248);            // 25,165,824 (end ~65.7 MB)
    unsigned short* wsOb  = (unsigned short*)wsTmp;             // bf16 attn-out (reuses wsTmp)

    // both weight transposes in one launch
    wt2_k<<<dim3(24, 32, 2), 256, 0, stream>>>(Wl, Wq, wsWlt, wsWqt, layer);
    // both GEMMs in one launch: z=0 proj (fp32 -> wsTmp), z=1 q (bf16 -> wsQ)
    gemm_dual<<<dim3(128, 8, 2), 256, 0, stream>>>(Fs, wsWlt, wsTmp, Ft, wsWqt, wsQ, bq, SCALE_F);
    // F_s_p = normalize(proj) -> out1 (fp32) + wsKV (bf16)
    rownorm_k<<<2048, 256, 0, stream>>>(wsTmp, out1, wsKV);
    kvt_k<<<dim3(64, 3, 32), 256, 0, stream>>>(wsKV, wsKVT);
    // attention -> wsOb (bf16, pre-residual; overwrites wsTmp after rownorm consumed it)
    attn_k<<<256, 512, 0, stream>>>(wsQ, wsKV, wsKVT, wsOb);
    // out0 = normalize(attn_out + F_t)
    resid_norm_k<<<2048, 256, 0, stream>>>(wsOb, Ft, out0);
}

// Round 26
// 145.250 us; speedup vs baseline: 1.3521x; 1.3521x over previous
//
#include <hip/hip_runtime.h>

using short8 = __attribute__((ext_vector_type(8))) short;
using f32x4  = __attribute__((ext_vector_type(4))) float;

#define DEV __device__ __forceinline__

#define GLBP(p) ((const __attribute__((address_space(1))) unsigned int*)(p))
#define LDSP(p) ((__attribute__((address_space(3))) unsigned int*)(p))

#define EXP2F(x) __builtin_amdgcn_exp2f(x)

// float -> bf16 round-to-nearest-even (finite inputs)
DEV unsigned short f2bf(float f) {
    unsigned int u = __float_as_uint(f);
    u += 0x7fffu + ((u >> 16) & 1u);
    return (unsigned short)(u >> 16);
}

// pack two floats into 2 bf16 (RNE), lo | hi<<16
DEV unsigned int pack2bf(float a, float b) {
    unsigned int ua = __float_as_uint(a);
    ua += 0x7fffu + ((ua >> 16) & 1u);
    unsigned int ub = __float_as_uint(b);
    ub += 0x7fffu + ((ub >> 16) & 1u);
    return (ua >> 16) | (ub & 0xffff0000u);
}

// ---------------------------------------------------------------- converts
// merged transpose+convert for BOTH weights: z=0 -> W_lin[layer] (1024x768),
// z=1 -> W_q (768x768).  out bf16 [C][R].
__global__ __launch_bounds__(256) void wt2_k(const float* __restrict__ Wl,
                                             const float* __restrict__ Wq,
                                             unsigned short* __restrict__ outl,
                                             unsigned short* __restrict__ outq,
                                             const int* __restrict__ layerp) {
    const int z = blockIdx.z;
    int R, C;
    const float* in;
    unsigned short* out;
    if (z == 0) {
        R = 1024; C = 768;
        in = Wl + (size_t)layerp[0] * (1024 * 768);
        out = outl;
    } else {
        if (blockIdx.y >= 24) return;   // 768/32 = 24 row-tiles
        R = 768; C = 768;
        in = Wq;
        out = outq;
    }
    __shared__ float t[32][33];
    const int tx = threadIdx.x & 31, ty = threadIdx.x >> 5;
    const int c0 = blockIdx.x * 32, r0 = blockIdx.y * 32;
#pragma unroll
    for (int it = 0; it < 4; ++it)
        t[ty + it * 8][tx] = in[(size_t)(r0 + ty + it * 8) * C + c0 + tx];
    __syncthreads();
#pragma unroll
    for (int it = 0; it < 4; ++it)
        out[(size_t)(c0 + ty + it * 8) * R + r0 + tx] = f2bf(t[tx][ty + it * 8]);
}

// bf16 [b][2048][H*96] -> bf16 [b*H + h][96][2048]
__global__ __launch_bounds__(256) void kvt_k(const unsigned short* __restrict__ kv,
                                             unsigned short* __restrict__ kvT) {
    const int n0 = blockIdx.x * 32, d0 = blockIdx.y * 32, bh = blockIdx.z;
    const int b = bh >> 3, h = bh & 7;
    __shared__ unsigned short t[32][33];
    const int tx = threadIdx.x & 31, ty = threadIdx.x >> 5;
#pragma unroll
    for (int it = 0; it < 4; ++it)
        t[ty + it * 8][tx] = kv[(size_t)(b * 2048 + n0 + ty + it * 8) * 768 + h * 96 + d0 + tx];
    __syncthreads();
#pragma unroll
    for (int it = 0; it < 4; ++it)
        kvT[((size_t)bh * 96 + d0 + ty + it * 8) * 2048 + n0 + tx] = t[tx][ty + it * 8];
}

// ---------------------------------------------------------------- GEMM (dual)
// One launch, grid (64, 8, 2).  z=0: proj = Fs @ Wlt -> fp32 C0.  z=1: q =
// (Ft @ Wqt + bias)*oscale -> bf16 C1.  128x96 tile, 4 waves 2x2, wave 64x48,
// acc[4][3], BK=32.  B via global_load_lds (linear dest); A reg-staged with
// fused fp32->bf16 convert.  [Measured best: 75.5us; tile/occupancy/conflict
// variants R22-R25 all null or negative — 2-barrier structure is the floor.]
__global__ __launch_bounds__(256) void gemm_dual(const float* __restrict__ A0,
                                                 const unsigned short* __restrict__ B0,
                                                 float* __restrict__ C0,
                                                 const float* __restrict__ A1,
                                                 const unsigned short* __restrict__ B1,
                                                 unsigned short* __restrict__ C1,
                                                 const float* __restrict__ bias,
                                                 float oscale) {
    __shared__ unsigned short smA[4096];   // (kg*128 + row)*8
    __shared__ unsigned short smB[3072];   // (kg*96  + row)*8
    const int z = blockIdx.z;
    const float* A = z ? A1 : A0;
    const unsigned short* B = z ? B1 : B0;
    const int K = z ? 768 : 1024;
    const int tid = threadIdx.x, lane = tid & 63;
    const int l15 = lane & 15, g = lane >> 4;
    const int w = tid >> 6, wm = w >> 1, wn = w & 1;
    const int m0 = blockIdx.x * 128, n0 = blockIdx.y * 96;
    const int srow = tid >> 2, skg = tid & 3;
    const int brow0 = tid % 96, bkg0 = tid / 96;
    const int c1 = tid + 256;
    const int brow1 = c1 % 96, bkg1 = c1 / 96;
    const unsigned short* pB0 = B + (size_t)(n0 + brow0) * K + bkg0 * 8;
    const unsigned short* pB1 = B + (size_t)(n0 + brow1) * K + bkg1 * 8;
    f32x4 acc[4][3] = {};
    const int nkt = K >> 5;
    for (int kt = 0; kt < nkt; ++kt) {
        const int k0 = kt << 5;
        __syncthreads();
        {
            __builtin_amdgcn_global_load_lds(GLBP(pB0 + k0), LDSP(smB + tid * 8), 16, 0, 0);
            if (tid < 128)
                __builtin_amdgcn_global_load_lds(GLBP(pB1 + k0), LDSP(smB + c1 * 8), 16, 0, 0);
            const float* p0 = A + (size_t)(m0 + srow) * K + k0 + skg * 8;
            const float* p1 = A + (size_t)(m0 + 64 + srow) * K + k0 + skg * 8;
            float4 a0 = *(const float4*)p0, a0b = *(const float4*)(p0 + 4);
            float4 a1 = *(const float4*)p1, a1b = *(const float4*)(p1 + 4);
            short8 va0, va1;
            va0[0] = f2bf(a0.x);  va0[1] = f2bf(a0.y);  va0[2] = f2bf(a0.z);  va0[3] = f2bf(a0.w);
            va0[4] = f2bf(a0b.x); va0[5] = f2bf(a0b.y); va0[6] = f2bf(a0b.z); va0[7] = f2bf(a0b.w);
            va1[0] = f2bf(a1.x);  va1[1] = f2bf(a1.y);  va1[2] = f2bf(a1.z);  va1[3] = f2bf(a1.w);
            va1[4] = f2bf(a1b.x); va1[5] = f2bf(a1b.y); va1[6] = f2bf(a1b.z); va1[7] = f2bf(a1b.w);
            *(short8*)(smA + (skg * 128 + srow) * 8) = va0;
            *(short8*)(smA + (skg * 128 + 64 + srow) * 8) = va1;
        }
        __syncthreads();
        short8 af[4], bf[3];
#pragma unroll
        for (int i = 0; i < 4; ++i)
            af[i] = *(const short8*)(smA + (g * 128 + wm * 64 + i * 16 + l15) * 8);
#pragma unroll
        for (int j = 0; j < 3; ++j)
            bf[j] = *(const short8*)(smB + (g * 96 + wn * 48 + j * 16 + l15) * 8);
#pragma unroll
        for (int i = 0; i < 4; ++i)
#pragma unroll
            for (int j = 0; j < 3; ++j)
                acc[i][j] = __builtin_amdgcn_mfma_f32_16x16x32_bf16(af[i], bf[j], acc[i][j], 0, 0, 0);
    }
#pragma unroll
    for (int j = 0; j < 3; ++j) {
        const int col = n0 + wn * 48 + j * 16 + l15;
        const float bv = z ? bias[col] : 0.0f;
#pragma unroll
        for (int i = 0; i < 4; ++i)
#pragma unroll
            for (int r = 0; r < 4; ++r) {
                const int row = m0 + wm * 64 + i * 16 + g * 4 + r;
                if (z == 0) {
                    C0[(size_t)row * 768 + col] = acc[i][j][r];
                } else {
                    const float v = (acc[i][j][r] + bv) * oscale;
                    C1[(size_t)row * 768 + col] = f2bf(v);
                }
            }
    }
}

// ---------------------------------------------------------------- row norms
// one wave per 768-elem row
__global__ __launch_bounds__(256) void rownorm_k(const float* __restrict__ in,
                                                 float* __restrict__ outf,
                                                 unsigned short* __restrict__ outb) {
    const int lane = threadIdx.x & 63;
    const int row = blockIdx.x * 4 + (threadIdx.x >> 6);
    const float* p = in + (size_t)row * 768;
    float4 v[3];
    float s = 0.f;
#pragma unroll
    for (int i = 0; i < 3; ++i) {
        v[i] = ((const float4*)p)[i * 64 + lane];
        s += v[i].x * v[i].x + v[i].y * v[i].y + v[i].z * v[i].z + v[i].w * v[i].w;
    }
#pragma unroll
    for (int mask = 1; mask < 64; mask <<= 1) s += __shfl_xor(s, mask);
    const float inv = rsqrtf(s);
    float4* of = (float4*)(outf + (size_t)row * 768);
    ushort4* ob = (ushort4*)(outb + (size_t)row * 768);
#pragma unroll
    for (int i = 0; i < 3; ++i) {
        float4 q;
        q.x = v[i].x * inv; q.y = v[i].y * inv; q.z = v[i].z * inv; q.w = v[i].w * inv;
        of[i * 64 + lane] = q;
        ushort4 u;
        u.x = f2bf(q.x); u.y = f2bf(q.y); u.z = f2bf(q.z); u.w = f2bf(q.w);
        ob[i * 64 + lane] = u;
    }
}

// residual + L2 norm; attn-out is bf16 (halved traffic), residual Ft is fp32
__global__ __launch_bounds__(256) void resid_norm_k(const unsigned short* __restrict__ in,
                                                    const float* __restrict__ res,
                                                    float* __restrict__ outf) {
    const int lane = threadIdx.x & 63;
    const int row = blockIdx.x * 4 + (threadIdx.x >> 6);
    const ushort4* pa = (const ushort4*)(in + (size_t)row * 768);
    const float4* pb = (const float4*)(res + (size_t)row * 768);
    float4 v[3];
    float s = 0.f;
#pragma unroll
    for (int i = 0; i < 3; ++i) {
        ushort4 a = pa[i * 64 + lane];
        float4 b = pb[i * 64 + lane];
        float4 c;
        c.x = __uint_as_float((unsigned int)a.x << 16) + b.x;
        c.y = __uint_as_float((unsigned int)a.y << 16) + b.y;
        c.z = __uint_as_float((unsigned int)a.z << 16) + b.z;
        c.w = __uint_as_float((unsigned int)a.w << 16) + b.w;
        v[i] = c;
        s += c.x * c.x + c.y * c.y + c.z * c.z + c.w * c.w;
    }
#pragma unroll
    for (int mask = 1; mask < 64; mask <<= 1) s += __shfl_xor(s, mask);
    const float inv = rsqrtf(s);
    float4* of = (float4*)(outf + (size_t)row * 768);
#pragma unroll
    for (int i = 0; i < 3; ++i) {
        float4 q;
        q.x = v[i].x * inv; q.y = v[i].y * inv; q.z = v[i].z * inv; q.w = v[i].w * inv;
        of[i * 64 + lane] = q;
    }
}

// ---------------------------------------------------------------- fused attention
// grid = 256 (XCD-swizzled) = 1 block/CU; 8 waves x 32 q-rows (256 q/block).
// KV chunk = 64; K and V^T double-buffered in LDS via global_load_lds (R14 verified).
// R15: softmax denominator in the matrix pipe (o6 = P x ones MFMA).
// R18: bf16 output.  R19: no max tracking (scores provably bounded ~0.42 log2-units).
__global__ __launch_bounds__(512) void attn_k(const unsigned short* __restrict__ Q,
                                              const unsigned short* __restrict__ KV,
                                              const unsigned short* __restrict__ KVT,
                                              unsigned short* __restrict__ O) {
    __shared__ unsigned short sK[2][6144];   // 12 KiB per buffer
    __shared__ unsigned short sV[2][6144];   // 12 KiB per buffer
    __shared__ unsigned short plds[8][32][72];
    // bijective XCD swizzle for nwg=256: XCD x gets bids [x*32, (x+1)*32)
    const int hw = blockIdx.x;
    const int bid = (hw & 7) * 32 + (hw >> 3);
    const int qb = bid & 7, h = (bid >> 3) & 7, b = bid >> 6;
    const int tid = threadIdx.x, lane = tid & 63, w = tid >> 6;   // w = 0..7
    const int l15 = lane & 15, g = lane >> 4;
    const int q0 = qb * 256 + w * 32;
    unsigned short(*pw)[72] = plds[w];

    const unsigned short* kb = KV + (size_t)(b * 2048) * 768 + h * 96;
    const unsigned short* vb = KVT + (size_t)((b * 8 + h) * 96) * 2048;

    // all-ones bf16 B-operand for the l = P x 1 MFMA
    const short8 kOnes = {(short)0x3F80, (short)0x3F80, (short)0x3F80, (short)0x3F80,
                          (short)0x3F80, (short)0x3F80, (short)0x3F80, (short)0x3F80};

    // Q fragments (B-operand): q = q0 + mi*16 + l15, d = ks*32 + g*8
    short8 aq[2][3];
#pragma unroll
    for (int mi = 0; mi < 2; ++mi) {
        const unsigned short* qp = Q + (size_t)(b * 2048 + q0 + mi * 16 + l15) * 768 + h * 96 + g * 8;
#pragma unroll
        for (int ks = 0; ks < 3; ++ks) aq[mi][ks] = *(const short8*)(qp + ks * 32);
    }
    f32x4 o[2][6] = {};
    f32x4 o6[2] = {};                 // row-sum accumulator (softmax denominator)

    // ---- staging descriptors: 24 x 1KB loads, 3 per wave (li = p*8 + w).
    // li 0..11: K, ksub = li, r = lane.  li 12..23: V, j = li-12, i = j*64+lane.
    const unsigned short* sgp[3];
    int sstep[3], soff[3], sisk[3];
#pragma unroll
    for (int p = 0; p < 3; ++p) {
        const int li = p * 8 + w;   // wave-uniform
        if (li < 12) {
            sgp[p] = kb + (size_t)lane * 768 + li * 8;
            sstep[p] = 64 * 768;
            soff[p] = li * 512;     // shorts
            sisk[p] = 1;
        } else {
            const int j = li - 12;
            const int i = j * 64 + lane;
            const int kvsub = i / 96, d = i - kvsub * 96;
            sgp[p] = vb + (size_t)d * 2048 + kvsub * 8;
            sstep[p] = 64;
            soff[p] = j * 512;
            sisk[p] = 0;
        }
    }
    auto stage = [&](unsigned short* sKb, unsigned short* sVb) {
#pragma unroll
        for (int p = 0; p < 3; ++p) {
            __builtin_amdgcn_global_load_lds(GLBP(sgp[p]), LDSP((sisk[p] ? sKb : sVb) + soff[p]), 16, 0, 0);
            sgp[p] += sstep[p];
        }
    };

    stage(sK[0], sV[0]);
    __syncthreads();   // drains vmcnt, buffer 0 ready

    for (int c = 0; c < 32; ++c) {
        const int cur = c & 1;
        const unsigned short* sKb = sK[cur];
        const unsigned short* sVb = sV[cur];
        if (c < 31) stage(sK[cur ^ 1], sV[cur ^ 1]);

        // ---- QK^T (swapped): S^T[kv][q], q = mi*16 + l15 lane-local ----
        f32x4 s[2][4];
        __builtin_amdgcn_s_setprio(1);
#pragma unroll
        for (int t = 0; t < 4; ++t) {
            short8 k0 = *(const short8*)(sKb + ((0 + g) * 64 + t * 16 + l15) * 8);
            short8 k1 = *(const short8*)(sKb + ((4 + g) * 64 + t * 16 + l15) * 8);
            short8 k2 = *(const short8*)(sKb + ((8 + g) * 64 + t * 16 + l15) * 8);
#pragma unroll
            for (int mi = 0; mi < 2; ++mi) {
                f32x4 a = {};
                a = __builtin_amdgcn_mfma_f32_16x16x32_bf16(k0, aq[mi][0], a, 0, 0, 0);
                a = __builtin_amdgcn_mfma_f32_16x16x32_bf16(k1, aq[mi][1], a, 0, 0, 0);
                a = __builtin_amdgcn_mfma_f32_16x16x32_bf16(k2, aq[mi][2], a, 0, 0, 0);
                s[mi][t] = a;
            }
        }
        __builtin_amdgcn_s_setprio(0);
        // ---- softmax numerator: P = exp2(s), un-shifted (scores bounded ~0.42) ----
#pragma unroll
        for (int mi = 0; mi < 2; ++mi) {
#pragma unroll
            for (int t = 0; t < 4; ++t)
#pragma unroll
                for (int r = 0; r < 4; ++r)
                    s[mi][t][r] = EXP2F(s[mi][t][r]);
            // write P^T -> P[q][kv] (one ds_write_b64 per (mi,t))
#pragma unroll
            for (int t = 0; t < 4; ++t) {
                uint2 pk;
                pk.x = pack2bf(s[mi][t][0], s[mi][t][1]);
                pk.y = pack2bf(s[mi][t][2], s[mi][t][3]);
                *(uint2*)&pw[mi * 16 + l15][t * 16 + g * 4] = pk;
            }
        }
        // ---- PV: O[q][d] += P[q][kv] * V^T[d][kv];  l += P x ones ----
        __builtin_amdgcn_s_setprio(1);
#pragma unroll
        for (int half = 0; half < 2; ++half) {
            short8 pa[2];
#pragma unroll
            for (int mi = 0; mi < 2; ++mi) {
                pa[mi] = *(const short8*)&pw[mi * 16 + l15][half * 32 + g * 8];
                o6[mi] = __builtin_amdgcn_mfma_f32_16x16x32_bf16(pa[mi], kOnes, o6[mi], 0, 0, 0);
            }
#pragma unroll
            for (int dt = 0; dt < 6; ++dt) {
                short8 bv = *(const short8*)(sVb + ((half * 4 + g) * 96 + dt * 16 + l15) * 8);
#pragma unroll
                for (int mi = 0; mi < 2; ++mi)
                    o[mi][dt] = __builtin_amdgcn_mfma_f32_16x16x32_bf16(pa[mi], bv, o[mi][dt], 0, 0, 0);
            }
        }
        __builtin_amdgcn_s_setprio(0);
        __syncthreads();   // drains staging vmcnt; next buffer ready, this buffer free
    }
    // epilogue: normalize rows; denominator per-lane in o6; bf16 output
#pragma unroll
    for (int mi = 0; mi < 2; ++mi)
#pragma unroll
        for (int r = 0; r < 4; ++r) {
            const float inv = 1.0f / o6[mi][r];
            unsigned short* op = O + (size_t)(b * 2048 + q0 + mi * 16 + g * 4 + r) * 768 + h * 96 + l15;
#pragma unroll
            for (int dt = 0; dt < 6; ++dt) op[dt * 16] = f2bf(o[mi][dt][r] * inv);
        }
}

// ---------------------------------------------------------------- launch
// SCALE * log2(e): softmax runs in exp2 domain
#define SCALE_F 0.05205877254075156f

extern "C" void kernel_launch(void* const* d_in, const int* in_sizes, int n_in,
                              void* d_out, int out_size, void* d_ws, size_t ws_size,
                              hipStream_t stream) {
    const float* Ft = (const float*)d_in[0];   // [4,2048,768]
    const float* Fs = (const float*)d_in[1];   // [4,2048,1024]
    const float* Wl = (const float*)d_in[2];   // [4,1024,768]
    const float* Wq = (const float*)d_in[3];   // [768,768]
    const float* bq = (const float*)d_in[4];   // [768]
    const int* layer = (const int*)d_in[5];    // scalar

    float* out0 = (float*)d_out;               // F_t_a [4,2048,768]
    float* out1 = out0 + 6291456;              // F_s_p [4,2048,768]

    char* ws = (char*)d_ws;
    unsigned short* wsQ   = (unsigned short*)(ws);              // 12,582,912 B
    unsigned short* wsWlt = (unsigned short*)(ws + 12582912);   //  1,572,864
    unsigned short* wsWqt = (unsigned short*)(ws + 14155776);   //  1,179,648
    unsigned short* wsKV  = (unsigned short*)(ws + 15335424);   // 12,582,912
    unsigned short* wsKVT = (unsigned short*)(ws + 27918336);   // 12,582,912
    float*          wsTmp = (float*)(ws + 40501248);            // 25,165,824 (end ~65.7 MB)
    unsigned short* wsOb  = (unsigned short*)wsTmp;             // bf16 attn-out (reuses wsTmp)

    // both weight transposes in one launch
    wt2_k<<<dim3(24, 32, 2), 256, 0, stream>>>(Wl, Wq, wsWlt, wsWqt, layer);
    // both GEMMs in one launch: z=0 proj (fp32 -> wsTmp), z=1 q (bf16 -> wsQ)
    gemm_dual<<<dim3(64, 8, 2), 256, 0, stream>>>(Fs, wsWlt, wsTmp, Ft, wsWqt, wsQ, bq, SCALE_F);
    // F_s_p = normalize(proj) -> out1 (fp32) + wsKV (bf16)
    rownorm_k<<<2048, 256, 0, stream>>>(wsTmp, out1, wsKV);
    kvt_k<<<dim3(64, 3, 32), 256, 0, stream>>>(wsKV, wsKVT);
    // attention -> wsOb (bf16, pre-residual; overwrites wsTmp after rownorm consumed it)
    attn_k<<<256, 512, 0, stream>>>(wsQ, wsKV, wsKVT, wsOb);
    // out0 = normalize(attn_out + F_t)
    resid_norm_k<<<2048, 256, 0, stream>>>(wsOb, Ft, out0);
}